// Round 1
// baseline (352.785 us; speedup 1.0000x reference)
//
#include <hip/hip_runtime.h>
#include <hip/hip_bf16.h>

// FeatureOptimalLoss: Sinkhorn with L1 cost, n=2048, d=64, eps=100, 10 iters.
// out = sum(exp((-C + u_i + v_j)/eps) * C), scalar f32.

#define N 2048
#define D 64
#define EPS 100.0f
#define INV_EPS 0.01f
// log(1/2048) = -11*log(2)
#define LOG_MU (-7.6246189861593985f)

__device__ __forceinline__ float block_reduce_sum_256(float x) {
    // wave64 shuffle reduce, then cross-wave via LDS. blockDim.x must be 256.
    #pragma unroll
    for (int off = 32; off > 0; off >>= 1) x += __shfl_down(x, off, 64);
    __shared__ float sh[4];
    int lane = threadIdx.x & 63;
    int w = threadIdx.x >> 6;
    if (lane == 0) sh[w] = x;
    __syncthreads();
    float r = 0.f;
    if (threadIdx.x == 0) r = sh[0] + sh[1] + sh[2] + sh[3];
    __syncthreads();  // make helper safely reusable
    return r;         // valid on thread 0 only
}

// ---------------- C matrix: C[i][j] = sum_k |A[i][k] - B[j][k]| ----------------
__global__ __launch_bounds__(256) void compute_C_kernel(
    const float* __restrict__ A, const float* __restrict__ B, float* __restrict__ C) {
    __shared__ float As[64][65];  // +1 pad: odd stride -> conflict-free column reads
    __shared__ float Bs[64][65];
    const int i0 = blockIdx.y * 64, j0 = blockIdx.x * 64;
    const int tid = threadIdx.x;
    #pragma unroll
    for (int e = 0; e < 16; ++e) {
        int idx = e * 256 + tid;
        int r = idx >> 6, c = idx & 63;
        As[r][c] = A[(size_t)(i0 + r) * D + c];
        Bs[r][c] = B[(size_t)(j0 + r) * D + c];
    }
    __syncthreads();
    #pragma unroll
    for (int e = 0; e < 16; ++e) {
        int idx = e * 256 + tid;
        int li = idx >> 6, lj = idx & 63;  // lj consecutive across lanes -> Bs conflict-free
        float s = 0.f;
        #pragma unroll
        for (int k = 0; k < 64; ++k) s += fabsf(As[li][k] - Bs[lj][k]);
        C[(size_t)(i0 + li) * N + (j0 + lj)] = s;
    }
}

// ---------------- init: u = v = 0, done = 0 ----------------
__global__ void init_kernel(float* u, float* v, int* done) {
    int t = blockIdx.x * blockDim.x + threadIdx.x;
    if (t < N) { u[t] = 0.f; v[t] = 0.f; }
    if (t == 0) *done = 0;
}

// ---------------- row pass: u_new[i] = eps*(log_mu - lse_row_i) + u[i] ----------------
__global__ __launch_bounds__(256) void lse_row_kernel(
    const float* __restrict__ C, const float* __restrict__ u,
    const float* __restrict__ v, float* __restrict__ u_new) {
    const int i = blockIdx.x;
    const float ui = u[i];
    const float* Crow = C + (size_t)i * N;
    float s = 0.f;
    for (int j = threadIdx.x; j < N; j += 256)
        s += expf((ui + v[j] - Crow[j]) * INV_EPS);
    s = block_reduce_sum_256(s);
    if (threadIdx.x == 0)
        u_new[i] = EPS * (LOG_MU - logf(s + 1e-6f)) + ui;
}

// ---------------- col pass (tiled partials): sum_i exp(M[i][j]) ----------------
// grid (32 col-tiles, 16 row-tiles), block 256 = 64 cols x 4 row-lanes.
__global__ __launch_bounds__(256) void col_partial_kernel(
    const float* __restrict__ C, const float* __restrict__ u_new,
    const float* __restrict__ v, float* __restrict__ part) {
    const int j0 = blockIdx.x * 64;
    const int i0 = blockIdx.y * 128;
    const int c = threadIdx.x & 63;
    const int rl = threadIdx.x >> 6;  // 0..3
    const int j = j0 + c;
    const float vj = v[j];
    float s = 0.f;
    for (int si = rl; si < 128; si += 4) {
        int i = i0 + si;
        // wave reads 64 consecutive C elems of row i -> coalesced
        s += expf((u_new[i] + vj - C[(size_t)i * N + j]) * INV_EPS);
    }
    __shared__ float sh[4][64];
    sh[rl][c] = s;
    __syncthreads();
    if (threadIdx.x < 64) {
        int cc = threadIdx.x;
        part[(size_t)blockIdx.y * N + j0 + cc] =
            sh[0][cc] + sh[1][cc] + sh[2][cc] + sh[3][cc];
    }
}

__global__ __launch_bounds__(256) void col_finish_kernel(
    const float* __restrict__ part, const float* __restrict__ v,
    float* __restrict__ v_new) {
    const int j = blockIdx.x * 256 + threadIdx.x;
    float s = 0.f;
    #pragma unroll
    for (int t = 0; t < 16; ++t) s += part[(size_t)t * N + j];
    v_new[j] = EPS * (LOG_MU - logf(s + 1e-6f)) + v[j];
}

// ---------------- per-iteration finalize: err, freeze-select, done update ----------------
__global__ __launch_bounds__(256) void finalize_kernel(
    float* __restrict__ u, float* __restrict__ v,
    const float* __restrict__ u_new, const float* __restrict__ v_new,
    int* __restrict__ done) {
    float e = 0.f;
    for (int j = threadIdx.x; j < N; j += 256) e += fabsf(u_new[j] - u[j]);
    e = block_reduce_sum_256(e);
    __shared__ float err_sh;
    __shared__ int done_sh;
    if (threadIdx.x == 0) { err_sh = e; done_sh = *done; }
    __syncthreads();
    if (!done_sh) {
        for (int j = threadIdx.x; j < N; j += 256) { u[j] = u_new[j]; v[j] = v_new[j]; }
    }
    if (threadIdx.x == 0 && err_sh < 0.1f) *done = 1;
}

// ---------------- final loss: sum exp(M) * C ----------------
__global__ __launch_bounds__(256) void loss_row_kernel(
    const float* __restrict__ C, const float* __restrict__ u,
    const float* __restrict__ v, float* __restrict__ rowpart) {
    const int i = blockIdx.x;
    const float ui = u[i];
    const float* Crow = C + (size_t)i * N;
    float s = 0.f;
    for (int j = threadIdx.x; j < N; j += 256) {
        float c = Crow[j];
        s += expf((ui + v[j] - c) * INV_EPS) * c;
    }
    s = block_reduce_sum_256(s);
    if (threadIdx.x == 0) rowpart[i] = s;
}

__global__ __launch_bounds__(256) void loss_reduce_kernel(
    const float* __restrict__ rowpart, float* __restrict__ out) {
    float s = 0.f;
    for (int j = threadIdx.x; j < N; j += 256) s += rowpart[j];
    s = block_reduce_sum_256(s);
    if (threadIdx.x == 0) out[0] = s;
}

extern "C" void kernel_launch(void* const* d_in, const int* in_sizes, int n_in,
                              void* d_out, int out_size, void* d_ws, size_t ws_size,
                              hipStream_t stream) {
    const float* A = (const float*)d_in[0];  // output [2048,64]
    const float* B = (const float*)d_in[1];  // target [2048,64]
    float* out = (float*)d_out;

    // workspace layout (bytes)
    char* base = (char*)d_ws;
    float* C      = (float*)base;                       // 2048*2048 f32 = 16 MiB
    float* u      = (float*)(base + (size_t)N * N * 4);
    float* v      = u + N;
    float* u_new  = v + N;
    float* v_new  = u_new + N;
    float* part   = v_new + N;                          // 16 * 2048 f32
    float* rowpart= part + 16 * N;                      // 2048 f32
    int*   done   = (int*)(rowpart + N);

    init_kernel<<<dim3(8), dim3(256), 0, stream>>>(u, v, done);
    compute_C_kernel<<<dim3(32, 32), dim3(256), 0, stream>>>(A, B, C);

    for (int it = 0; it < 10; ++it) {
        lse_row_kernel<<<dim3(N), dim3(256), 0, stream>>>(C, u, v, u_new);
        col_partial_kernel<<<dim3(32, 16), dim3(256), 0, stream>>>(C, u_new, v, part);
        col_finish_kernel<<<dim3(8), dim3(256), 0, stream>>>(part, v, v_new);
        finalize_kernel<<<dim3(1), dim3(256), 0, stream>>>(u, v, u_new, v_new, done);
    }

    loss_row_kernel<<<dim3(N), dim3(256), 0, stream>>>(C, u, v, rowpart);
    loss_reduce_kernel<<<dim3(1), dim3(256), 0, stream>>>(rowpart, out);
}